// Round 5
// baseline (138.509 us; speedup 1.0000x reference)
//
#include <hip/hip_runtime.h>
#include <hip/hip_bf16.h>

// z_{k+1} = tanh(z_k @ W^T + b + x), z_0 = 0, rows independent.
// Sigmoid reformulation: y = sigma(2h), z = 2y-1 =>
//   h' = 2*W*y + (x + b - rowsum(W))
//   W'' = 4*log2(e)*W (fp16, A-operand, register-resident)
//   xb  = 2*log2(e)*(x + b - rowsum(W)) (fp32, C-fragment layout)
//   y'  = rcp(1 + exp2(-S))
// Round 14: LDS-traffic halving. R13 accounting: per CU-batch the LDS pipe
// is the largest consumer (~65% busy: 16 waves x 16KiB re-read per sweep =
// 256KiB -> ~3.3k cyc of the 5.5k cyc sweep), VALU 38%, MFMA 35% -- nothing
// saturated, contention-bound. LDS reads scale as 1/(feats per wave): every
// wave re-reads the full K=256 operand for its rows. So: 64 feats/wave
// (halves LDS traffic AND halves waves at constant per-wave ILP). R12
// already tried 64 feats/wave and lost -- but to barrier lockstep and
// in-phase 2-WG trans collision, not the tiling. Here: ONE 512-thread WG,
// 8 waves = {row-tile wv>>2} x {feat-block wv&3}, fully async (only the
// init barrier), R13's prefetch pipeline kept. Accuracy: R11/R12 proved
// exact Jacobi @ NITER=10 sits on the fp16 quantization floor (0.0039);
// this scheme is >= Jacobi freshness (own block re-read after write = GS;
// foreign 6 ks prefetched early = Jacobi-or-better), static indexing via
// wave-uniform 4-case switches. Regs: wf 128 + zf 32 + acc 16 + xb 16 +
// temps ~= 210 -> fits (512,2) without spill.

#define BATCH   32768
#define FEAT    256
#define ROWS_WG 32
#define NITER   10

typedef _Float16 f16x8 __attribute__((ext_vector_type(8)));
typedef __fp16   h16x2 __attribute__((ext_vector_type(2)));
typedef float    f32x4 __attribute__((ext_vector_type(4)));

#define K4 5.7707801635558535f   // 4*log2(e)
#define K2 2.8853900817779268f   // 2*log2(e)

static __device__ __forceinline__ unsigned pkh(float a, float b) {
    h16x2 h = __builtin_amdgcn_cvt_pkrtz(a, b);
    return __builtin_bit_cast(unsigned, h);
}

// y = 1/(1 + 2^-s)
static __device__ __forceinline__ float sig_fast(float s) {
    float e = __builtin_amdgcn_exp2f(-s);
    return __builtin_amdgcn_rcpf(e + 1.0f);
}

// ---- Prep: W16 = K4*W (fp16, row-major) and rowsum (fp32), once. ----
__global__ __launch_bounds__(64)
void prep_kernel(const float* __restrict__ W,
                 unsigned short* __restrict__ W16,
                 float* __restrict__ rowsums)
{
    const int row = blockIdx.x;
    const int l   = threadIdx.x;
    f32x4 v = *(const f32x4*)(W + (unsigned)row * FEAT + l * 4);
    float s = (v[0] + v[1]) + (v[2] + v[3]);
#pragma unroll
    for (int off = 1; off < 64; off <<= 1) s += __shfl_xor(s, off);
    uint2 pk;
    pk.x = pkh(v[0] * K4, v[1] * K4);
    pk.y = pkh(v[2] * K4, v[3] * K4);
    *(uint2*)(W16 + (unsigned)row * FEAT + l * 4) = pk;
    if (l == 0) rowsums[row] = s;
}

__global__ __launch_bounds__(512, 2)
void IterativeFixedPoint_kernel(const float* __restrict__ X,
                                const unsigned short* __restrict__ W16,
                                const float* __restrict__ rowsums,
                                const float* __restrict__ Bv,
                                float* __restrict__ Out)
{
    // [row-half][ks][q][c][t] : B-fragment-packed, single buffer. 16 KiB.
    __shared__ unsigned short zbuf[2][8][4][16][8];

    const int tid  = threadIdx.x;
    const int wv   = tid >> 6;        // 0..7
    const int fb   = wv & 3;          // feat block: owns [64*fb, 64*fb+64)
    const int it   = wv >> 2;         // row-tile this wave updates
    const int lane = tid & 63;
    const int c    = lane & 15;       // batch-row within 16-tile / W output row
    const int q    = lane >> 4;       // quad id
    const int j0   = fb * 64;
    const int row0 = blockIdx.x * ROWS_WG + it * 16;

    // ---- Load W'' fragments (fp16, pre-scaled) straight from d_ws.
    f16x8 wf[4][8];
#pragma unroll
    for (int jt = 0; jt < 4; ++jt) {
        const unsigned short* wr = W16 + (unsigned)(j0 + jt * 16 + c) * FEAT;
#pragma unroll
        for (int ks = 0; ks < 8; ++ks)
            wf[jt][ks] = *(const f16x8*)(wr + ks * 32 + q * 8);
    }

    // ---- rowsums directly in C-fragment layout (element r = feat jt*16+q*4+r).
    f32x4 rsv[4];
#pragma unroll
    for (int jt = 0; jt < 4; ++jt)
        rsv[jt] = *(const f32x4*)(rowsums + j0 + jt * 16 + q * 4);

    // ---- xb = K2*(x + b - rowsum), own row-tile only.
    f32x4 xb[4];
    {
        const float* xr = X + (unsigned)(row0 + c) * FEAT + j0;
#pragma unroll
        for (int jt = 0; jt < 4; ++jt) {
            f32x4 xv = *(const f32x4*)(xr + jt * 16 + q * 4);
            f32x4 bv = *(const f32x4*)(Bv + j0 + jt * 16 + q * 4);
            xb[jt] = (xv + bv - rsv[jt]) * K2;
        }
    }

    // Fragment-packed write: C element (jt, r) of lane (c,q) is feature
    // f = 64*fb + 16*jt + 4*q + r = 32*ks' + 8*q' + t with
    //   ks' = 2*fb + (jt>>1),  q' = 2*(jt&1) + (q>>1),  t = 4*(q&1) + r.
#define ZWRITE(JT, PK)                                                         \
    *(uint2*)&zbuf[it][2 * fb + ((JT) >> 1)][2 * ((JT) & 1) + (q >> 1)]        \
                   [c][(q & 1) * 4] = (PK)

#define RD(K) zf[K] = *(const f16x8*)&zbuf[it][K][q][c][0];

    // ---- Iteration 1: S1 = xb + K2*rowsum;  y1 = sigma(S1).
#pragma unroll
    for (int jt = 0; jt < 4; ++jt) {
        f32x4 S = xb[jt] + K2 * rsv[jt];
        uint2 pk;
        pk.x = pkh(sig_fast(S[0]), sig_fast(S[1]));
        pk.y = pkh(sig_fast(S[2]), sig_fast(S[3]));
        ZWRITE(jt, pk);
    }
    __syncthreads();   // the only barrier: init globally visible

    // ---- Persistent B-fragment registers (own row-tile, full K).
    f16x8 zf[8];
    RD(0) RD(1) RD(2) RD(3) RD(4) RD(5) RD(6) RD(7)

    // ---- Sweeps 2..NITER-1: async, barrier-free.
    // Per sweep: MFMA chain (4 indep jt-chains) -> early prefetch of the 6
    // foreign ks (hidden under sigmoid; Jacobi-or-better freshness) ->
    // sigmoid+pack+write own block -> re-read own 2 ks (exact GS freshness).
    // Wave-uniform switch keeps all zf indexing compile-time (rule #20).
    for (int iter = 0; iter < NITER - 2; ++iter) {
        f32x4 acc[4];
        __builtin_amdgcn_s_setprio(1);
#pragma unroll
        for (int jt = 0; jt < 4; ++jt)
            acc[jt] = __builtin_amdgcn_mfma_f32_16x16x32_f16(
                wf[jt][0], zf[0], xb[jt], 0, 0, 0);
#pragma unroll
        for (int ks = 1; ks < 8; ++ks) {
#pragma unroll
            for (int jt = 0; jt < 4; ++jt)
                acc[jt] = __builtin_amdgcn_mfma_f32_16x16x32_f16(
                    wf[jt][ks], zf[ks], acc[jt], 0, 0, 0);
        }
        __builtin_amdgcn_s_setprio(0);

        switch (fb) {   // early prefetch: foreign 6 fragments
        case 0:  RD(2) RD(3) RD(4) RD(5) RD(6) RD(7) break;
        case 1:  RD(0) RD(1) RD(4) RD(5) RD(6) RD(7) break;
        case 2:  RD(0) RD(1) RD(2) RD(3) RD(6) RD(7) break;
        default: RD(0) RD(1) RD(2) RD(3) RD(4) RD(5) break;
        }

#pragma unroll
        for (int jt = 0; jt < 4; ++jt) {
            uint2 pk;
            pk.x = pkh(sig_fast(acc[jt][0]), sig_fast(acc[jt][1]));
            pk.y = pkh(sig_fast(acc[jt][2]), sig_fast(acc[jt][3]));
            ZWRITE(jt, pk);
        }

        switch (fb) {   // late re-read: own 2 fragments (fresh)
        case 0:  RD(0) RD(1) break;
        case 1:  RD(2) RD(3) break;
        case 2:  RD(4) RD(5) break;
        default: RD(6) RD(7) break;
        }
    }

    // ---- Final sweep: z = 2*y - 1 in fp32, store to global.
    {
        f32x4 acc[4];
        __builtin_amdgcn_s_setprio(1);
#pragma unroll
        for (int jt = 0; jt < 4; ++jt)
            acc[jt] = __builtin_amdgcn_mfma_f32_16x16x32_f16(
                wf[jt][0], zf[0], xb[jt], 0, 0, 0);
#pragma unroll
        for (int ks = 1; ks < 8; ++ks) {
#pragma unroll
            for (int jt = 0; jt < 4; ++jt)
                acc[jt] = __builtin_amdgcn_mfma_f32_16x16x32_f16(
                    wf[jt][ks], zf[ks], acc[jt], 0, 0, 0);
        }
        __builtin_amdgcn_s_setprio(0);
#pragma unroll
        for (int jt = 0; jt < 4; ++jt) {
            f32x4 o;
#pragma unroll
            for (int r = 0; r < 4; ++r)
                o[r] = __builtin_fmaf(2.0f, sig_fast(acc[jt][r]), -1.0f);
            *(f32x4*)(Out + (unsigned)(row0 + c) * FEAT + j0 + jt * 16 +
                      q * 4) = o;
        }
    }
}

extern "C" void kernel_launch(void* const* d_in, const int* in_sizes, int n_in,
                              void* d_out, int out_size, void* d_ws, size_t ws_size,
                              hipStream_t stream) {
    (void)in_sizes; (void)n_in; (void)ws_size; (void)out_size;
    const float* X  = (const float*)d_in[0];
    const float* W  = (const float*)d_in[1];
    const float* Bv = (const float*)d_in[2];
    float* Out = (float*)d_out;
    unsigned short* W16 = (unsigned short*)d_ws;                  // 128 KiB
    float* rowsums = (float*)((char*)d_ws + FEAT * FEAT * 2);     // 1 KiB
    prep_kernel<<<dim3(FEAT), dim3(64), 0, stream>>>(W, W16, rowsums);
    IterativeFixedPoint_kernel<<<dim3(BATCH / ROWS_WG), dim3(512), 0, stream>>>(
        X, W16, rowsums, Bv, Out);
}

// Round 6
// 117.397 us; speedup vs baseline: 1.1798x; 1.1798x over previous
//
#include <hip/hip_runtime.h>
#include <hip/hip_bf16.h>

// z_{k+1} = tanh(z_k @ W^T + b + x), z_0 = 0, rows independent.
// Sigmoid reformulation: y = sigma(2h), z = 2y-1 =>
//   h' = 2*W*y + (x + b - rowsum(W))
//   W'' = 4*log2(e)*W (fp16, A-operand, register-resident)
//   xb  = 2*log2(e)*(x + b - rowsum(W)) (fp32, C-fragment layout)
//   y'  = rcp(1 + exp2(-S))
// Round 15: R13 (44.3us) is the confirmed structural optimum: 16 waves/CU,
// F=32 feats/wave. R11/R12/R14 closed the alternatives -- LDS traffic per
// output is K*2B/F for ANY shape, so raising F needs registers that drop
// occupancy below the latency-hiding floor (R14: 72us at 2 waves/SIMD, and
// full-sweep-stale foreign reads pushed absmax to 0.0186). Two remaining
// levers on R13, both taken here:
//  (1) NITER 10->9: R13 absmax 0.0063; one fewer sweep *~1.8 -> ~0.012,
//      1.6x margin under 0.02. Saves ~1/9.5 of the main loop.
//  (2) Wave-phase stagger: odd waves sweep tiles in opposite order
//      (t0 = wv&1), breaking the 16-wave LDS read-burst convoy that left
//      ~40% of the LDS pipe idle (LDS ~60% busy was the largest pipe).
//      Tile identity is wave-uniform and used ONLY in addresses (zbuf
//      index, output row); xb is split into statically-indexed xbF/xbS so
//      nothing hits scratch. Async scheme => order is semantically free.
// Structure otherwise identical to R13: async barrier-free Chazan-Miranker
// sweeps, split prefetch (early ks0..3 under sigmoid, late ks4..7 after
// write), s_setprio(1) around the MFMA cluster.

#define BATCH   32768
#define FEAT    256
#define ROWS_WG 32
#define NITER   9

typedef _Float16 f16x8 __attribute__((ext_vector_type(8)));
typedef __fp16   h16x2 __attribute__((ext_vector_type(2)));
typedef float    f32x4 __attribute__((ext_vector_type(4)));

#define K4 5.7707801635558535f   // 4*log2(e)
#define K2 2.8853900817779268f   // 2*log2(e)

static __device__ __forceinline__ unsigned pkh(float a, float b) {
    h16x2 h = __builtin_amdgcn_cvt_pkrtz(a, b);
    return __builtin_bit_cast(unsigned, h);
}

// y = 1/(1 + 2^-s)
static __device__ __forceinline__ float sig_fast(float s) {
    float e = __builtin_amdgcn_exp2f(-s);
    return __builtin_amdgcn_rcpf(e + 1.0f);
}

// ---- Prep: W16 = K4*W (fp16, row-major) and rowsum (fp32), once. ----
__global__ __launch_bounds__(64)
void prep_kernel(const float* __restrict__ W,
                 unsigned short* __restrict__ W16,
                 float* __restrict__ rowsums)
{
    const int row = blockIdx.x;
    const int l   = threadIdx.x;
    f32x4 v = *(const f32x4*)(W + (unsigned)row * FEAT + l * 4);
    float s = (v[0] + v[1]) + (v[2] + v[3]);
#pragma unroll
    for (int off = 1; off < 64; off <<= 1) s += __shfl_xor(s, off);
    uint2 pk;
    pk.x = pkh(v[0] * K4, v[1] * K4);
    pk.y = pkh(v[2] * K4, v[3] * K4);
    *(uint2*)(W16 + (unsigned)row * FEAT + l * 4) = pk;
    if (l == 0) rowsums[row] = s;
}

__global__ __launch_bounds__(512, 4)
void IterativeFixedPoint_kernel(const float* __restrict__ X,
                                const unsigned short* __restrict__ W16,
                                const float* __restrict__ rowsums,
                                const float* __restrict__ Bv,
                                float* __restrict__ Out)
{
    // [row-half][ks][q][c][t] : B-fragment-packed, single buffer. 16 KiB.
    __shared__ unsigned short zbuf[2][8][4][16][8];

    const int tid  = threadIdx.x;
    const int wv   = tid >> 6;        // 0..7, owns features [32*wv, 32*wv+32)
    const int lane = tid & 63;
    const int c    = lane & 15;       // batch-row within 16-tile / W output row
    const int q    = lane >> 4;       // quad id
    const int j0   = wv * 32;
    const int row0 = blockIdx.x * ROWS_WG;

    // Stagger: odd waves process tiles in opposite order. Tile ids t0/t1 are
    // wave-uniform ints used only in LDS/global ADDRESSES (never reg index).
    const int t0 = wv & 1;
    const int t1 = t0 ^ 1;

    // ---- Load W'' fragments (fp16, pre-scaled) straight from d_ws.
    f16x8 wf[2][8];
#pragma unroll
    for (int jt = 0; jt < 2; ++jt) {
        const unsigned short* wr = W16 + (unsigned)(j0 + jt * 16 + c) * FEAT;
#pragma unroll
        for (int ks = 0; ks < 8; ++ks)
            wf[jt][ks] = *(const f16x8*)(wr + ks * 32 + q * 8);
    }

    // ---- rowsums directly in C-fragment layout (element r = row jt*16+q*4+r).
    f32x4 rsv[2];
#pragma unroll
    for (int jt = 0; jt < 2; ++jt)
        rsv[jt] = *(const f32x4*)(rowsums + j0 + jt * 16 + q * 4);

    // ---- xb = K2*(x + b - rowsum), C-fragment layout.
    // xbF = first-processed tile (t0), xbS = second (t1): static reg arrays.
    f32x4 xbF[2], xbS[2];
    {
        const float* xrF = X + (unsigned)(row0 + t0 * 16 + c) * FEAT + j0;
        const float* xrS = X + (unsigned)(row0 + t1 * 16 + c) * FEAT + j0;
#pragma unroll
        for (int jt = 0; jt < 2; ++jt) {
            f32x4 bv = *(const f32x4*)(Bv + j0 + jt * 16 + q * 4);
            f32x4 xvF = *(const f32x4*)(xrF + jt * 16 + q * 4);
            f32x4 xvS = *(const f32x4*)(xrS + jt * 16 + q * 4);
            xbF[jt] = (xvF + bv - rsv[jt]) * K2;
            xbS[jt] = (xvS + bv - rsv[jt]) * K2;
        }
    }

    // Fragment-packed write: C element (jt, r) of lane (c,q) is feature
    // f = 32*wv + 16*jt + 4*q + r -> ks'=wv, q'=2*jt+(q>>1), t=4*(q&1)+r.
    // ITV is a runtime wave-uniform tile id (address only).
#define ZWRITE(ITV, JT, PK)                                                    \
    *(uint2*)&zbuf[ITV][wv][((JT) << 1) + (q >> 1)][c][(q & 1) * 4] = (PK)

    // ---- Iteration 1: S1 = xb + K2*rowsum;  y1 = sigma(S1).
#pragma unroll
    for (int jt = 0; jt < 2; ++jt) {
        f32x4 SF = xbF[jt] + K2 * rsv[jt];
        f32x4 SS = xbS[jt] + K2 * rsv[jt];
        uint2 pkF, pkS;
        pkF.x = pkh(sig_fast(SF[0]), sig_fast(SF[1]));
        pkF.y = pkh(sig_fast(SF[2]), sig_fast(SF[3]));
        pkS.x = pkh(sig_fast(SS[0]), sig_fast(SS[1]));
        pkS.y = pkh(sig_fast(SS[2]), sig_fast(SS[3]));
        ZWRITE(t0, jt, pkF);
        ZWRITE(t1, jt, pkS);
    }
    __syncthreads();   // the only barrier: ensure init is globally visible

    // ---- Persistent B-fragment registers; prologue: load first tile.
    f16x8 zf[8];
#pragma unroll
    for (int ks = 0; ks < 8; ++ks)
        zf[ks] = *(const f16x8*)&zbuf[t0][ks][q][c][0];

    // One async step on tile ITV (zf currently holds tile ITV):
    //   MFMA chain (setprio-wrapped) -> early prefetch of tile ITV^1 ks 0..3
    //   (hidden under sigmoid) -> sigmoid+pack+write(ITV) -> late prefetch
    //   ks 4..7 (first used ~4 MFMA stages into the next chain).
#define TILE_STEP(ITV, XB)                                                     \
    {                                                                          \
        f32x4 acc[2];                                                          \
        __builtin_amdgcn_s_setprio(1);                                         \
        _Pragma("unroll")                                                      \
        for (int jt = 0; jt < 2; ++jt)                                         \
            acc[jt] = __builtin_amdgcn_mfma_f32_16x16x32_f16(                  \
                wf[jt][0], zf[0], XB[jt], 0, 0, 0);                            \
        _Pragma("unroll")                                                      \
        for (int ks = 1; ks < 8; ++ks) {                                       \
            _Pragma("unroll")                                                  \
            for (int jt = 0; jt < 2; ++jt)                                     \
                acc[jt] = __builtin_amdgcn_mfma_f32_16x16x32_f16(              \
                    wf[jt][ks], zf[ks], acc[jt], 0, 0, 0);                     \
        }                                                                      \
        __builtin_amdgcn_s_setprio(0);                                         \
        _Pragma("unroll")                                                      \
        for (int ks = 0; ks < 4; ++ks)                                         \
            zf[ks] = *(const f16x8*)&zbuf[(ITV) ^ 1][ks][q][c][0];             \
        _Pragma("unroll")                                                      \
        for (int jt = 0; jt < 2; ++jt) {                                       \
            uint2 pk;                                                          \
            pk.x = pkh(sig_fast(acc[jt][0]), sig_fast(acc[jt][1]));            \
            pk.y = pkh(sig_fast(acc[jt][2]), sig_fast(acc[jt][3]));            \
            ZWRITE(ITV, jt, pk);                                               \
        }                                                                      \
        _Pragma("unroll")                                                      \
        for (int ks = 4; ks < 8; ++ks)                                         \
            zf[ks] = *(const f16x8*)&zbuf[(ITV) ^ 1][ks][q][c][0];             \
    }

    // ---- Sweeps 2..NITER-1: async, barrier-free, prefetch-pipelined.
    for (int iter = 0; iter < NITER - 2; ++iter) {
        TILE_STEP(t0, xbF)
        TILE_STEP(t1, xbS)
    }

    // ---- Final sweep: z = 2*y - 1 in fp32, store to global.
    // First consumes tile t0 (in zf), prefetches t1; second consumes t1.
#define FINAL_TILE(ITV, XB, PREFETCH)                                          \
    {                                                                          \
        f32x4 acc[2];                                                          \
        __builtin_amdgcn_s_setprio(1);                                         \
        _Pragma("unroll")                                                      \
        for (int jt = 0; jt < 2; ++jt)                                         \
            acc[jt] = __builtin_amdgcn_mfma_f32_16x16x32_f16(                  \
                wf[jt][0], zf[0], XB[jt], 0, 0, 0);                            \
        _Pragma("unroll")                                                      \
        for (int ks = 1; ks < 8; ++ks) {                                       \
            _Pragma("unroll")                                                  \
            for (int jt = 0; jt < 2; ++jt)                                     \
                acc[jt] = __builtin_amdgcn_mfma_f32_16x16x32_f16(              \
                    wf[jt][ks], zf[ks], acc[jt], 0, 0, 0);                     \
        }                                                                      \
        __builtin_amdgcn_s_setprio(0);                                         \
        if (PREFETCH) {                                                        \
            _Pragma("unroll")                                                  \
            for (int ks = 0; ks < 8; ++ks)                                     \
                zf[ks] = *(const f16x8*)&zbuf[(ITV) ^ 1][ks][q][c][0];         \
        }                                                                      \
        _Pragma("unroll")                                                      \
        for (int jt = 0; jt < 2; ++jt) {                                       \
            f32x4 o;                                                           \
            _Pragma("unroll")                                                  \
            for (int r = 0; r < 4; ++r)                                        \
                o[r] = __builtin_fmaf(2.0f, sig_fast(acc[jt][r]), -1.0f);      \
            *(f32x4*)(Out + (unsigned)(row0 + (ITV) * 16 + c) * FEAT +         \
                      j0 + jt * 16 + q * 4) = o;                               \
        }                                                                      \
    }

    FINAL_TILE(t0, xbF, 1)
    FINAL_TILE(t1, xbS, 0)
}

extern "C" void kernel_launch(void* const* d_in, const int* in_sizes, int n_in,
                              void* d_out, int out_size, void* d_ws, size_t ws_size,
                              hipStream_t stream) {
    (void)in_sizes; (void)n_in; (void)ws_size; (void)out_size;
    const float* X  = (const float*)d_in[0];
    const float* W  = (const float*)d_in[1];
    const float* Bv = (const float*)d_in[2];
    float* Out = (float*)d_out;
    unsigned short* W16 = (unsigned short*)d_ws;                  // 128 KiB
    float* rowsums = (float*)((char*)d_ws + FEAT * FEAT * 2);     // 1 KiB
    prep_kernel<<<dim3(FEAT), dim3(64), 0, stream>>>(W, W16, rowsums);
    IterativeFixedPoint_kernel<<<dim3(BATCH / ROWS_WG), dim3(512), 0, stream>>>(
        X, W16, rowsums, Bv, Out);
}